// Round 10
// baseline (289.649 us; speedup 1.0000x reference)
//
#include <hip/hip_runtime.h>
#include <hip/hip_bf16.h>

// Problem: B=2, S=2048, D=1024, H=16, DK=64
// out = concat_heads(softmax(mask(qk^T))v) @ Wu + bu
// Inputs fp32 (mask int32), output fp32. Internal: bf16.
//
// R10: attn = R8 2-wave form + t-split over 2 blocks (grid 2048, 25.6KB LDS
// -> block-level parallelism, which R9 showed is the limiter). Unnormalized
// softmax is tile-linear: splits write bf16 o-partials + fp32 lsum partials
// (aliasing dead vx/vb buffers), attn_merge combines. prep fuses
// cvt/wtrans/mask_pack into one launch.

typedef __bf16 bf16_t;
typedef __attribute__((ext_vector_type(4))) __bf16 bf16x4;
typedef __attribute__((ext_vector_type(8))) __bf16 bf16x8;
typedef __attribute__((ext_vector_type(4))) float f32x4;
typedef unsigned int u32;

#define B_ 2
#define S_ 2048
#define D_ 1024
#define H_ 16
#define DK_ 64
#define NX_ (4096 * 1024)

static __device__ __forceinline__ f32x4 mfma16(bf16x8 a, bf16x8 b, f32x4 c) {
  return __builtin_amdgcn_mfma_f32_16x16x32_bf16(a, b, c, 0, 0, 0);
}

// async global->LDS, 16B/lane; lds base wave-uniform, slot = base + lane*16
static __device__ __forceinline__ void async16(const bf16_t* g, bf16_t* l) {
  __builtin_amdgcn_global_load_lds(
      (const __attribute__((address_space(1))) u32*)g,
      (__attribute__((address_space(3))) u32*)l, 16, 0, 0);
}

// ---------------------------------------------------------------------------
// Fused prep. grid (2048, 5):
//   y=0..2: cvt q/k/v fp32->bf16 (x=0..2047)
//   y=3, x<1024: wtrans (d-tile = x&15, n-tile = (x>>4)&15, tensor = x>>8)
//   y=4, x<1024: mask_pack
// ---------------------------------------------------------------------------
__global__ __launch_bounds__(256) void prep(
    const float* __restrict__ q, const float* __restrict__ k,
    const float* __restrict__ v, const int* __restrict__ mask,
    const float* __restrict__ Wq, const float* __restrict__ Wk,
    const float* __restrict__ Wv, const float* __restrict__ Wu,
    bf16_t* __restrict__ qo, bf16_t* __restrict__ ko, bf16_t* __restrict__ vo,
    bf16_t* __restrict__ Bq, bf16_t* __restrict__ Bk,
    bf16_t* __restrict__ Bv, bf16_t* __restrict__ Bu,
    u32* __restrict__ bits, float qkscale) {
  __shared__ __align__(16) bf16_t T[64][72];
  const int y = blockIdx.y, x = blockIdx.x, tid = threadIdx.x;

  if (y < 3) {
    const float* src = (y == 0) ? q : (y == 1) ? k : v;
    bf16_t* dst = (y == 0) ? qo : (y == 1) ? ko : vo;
    size_t i = ((size_t)x * 256 + tid) * 8;
    float4 a = *(const float4*)(src + i);
    float4 b = *(const float4*)(src + i + 4);
    bf16x8 o;
    o[0] = (bf16_t)a.x; o[1] = (bf16_t)a.y; o[2] = (bf16_t)a.z; o[3] = (bf16_t)a.w;
    o[4] = (bf16_t)b.x; o[5] = (bf16_t)b.y; o[6] = (bf16_t)b.z; o[7] = (bf16_t)b.w;
    *(bf16x8*)(dst + i) = o;
  } else if (y == 3) {
    if (x >= 1024) return;
    const int z = x >> 8;
    const float* W = (z == 0) ? Wq : (z == 1) ? Wk : (z == 2) ? Wv : Wu;
    bf16_t* BT = (z == 0) ? Bq : (z == 1) ? Bk : (z == 2) ? Bv : Bu;
    const float scale = (z <= 1) ? qkscale : 1.0f;
    const int d0 = (x & 15) * 64, nt = (x >> 4) & 15;
    const int r = tid & 63, g = tid >> 6;
    const float* src = (z < 3)
        ? W + ((size_t)nt * D_ + d0 + r) * DK_ + g * 16
        : W + (size_t)(d0 + r) * D_ + nt * 64 + g * 16;
#pragma unroll
    for (int j = 0; j < 4; ++j) {
      float4 w4 = *(const float4*)(src + j * 4);
      T[g * 16 + j * 4 + 0][r] = (bf16_t)(w4.x * scale);
      T[g * 16 + j * 4 + 1][r] = (bf16_t)(w4.y * scale);
      T[g * 16 + j * 4 + 2][r] = (bf16_t)(w4.z * scale);
      T[g * 16 + j * 4 + 3][r] = (bf16_t)(w4.w * scale);
    }
    __syncthreads();
    const int orow = tid >> 3, seg = tid & 7;
#pragma unroll
    for (int p = 0; p < 2; ++p) {
      int rr = p * 32 + orow;
      *(bf16x8*)(BT + (size_t)(nt * 64 + rr) * D_ + d0 + seg * 8) =
          *(const bf16x8*)&T[rr][seg * 8];
    }
  } else {
    if (x >= 1024) return;
    int w = x * 256 + tid;
    const int4* p = (const int4*)(mask + (size_t)w * 32);
    u32 v2 = 0;
#pragma unroll
    for (int i = 0; i < 8; ++i) {
      int4 m4 = p[i];
      v2 |= (m4.x != 0 ? 1u : 0u) << (i * 4 + 0);
      v2 |= (m4.y != 0 ? 1u : 0u) << (i * 4 + 1);
      v2 |= (m4.z != 0 ? 1u : 0u) << (i * 4 + 2);
      v2 |= (m4.w != 0 ? 1u : 0u) << (i * 4 + 3);
    }
    bits[w] = v2;
  }
}

// ---------------------------------------------------------------------------
// V [4096][1024] bf16 -> Vt [1024][4096] bf16 (LDS-tiled transpose)
// ---------------------------------------------------------------------------
__global__ __launch_bounds__(256) void vt_build(const bf16_t* __restrict__ V,
                                                bf16_t* __restrict__ Vt) {
  __shared__ __align__(16) bf16_t T[64][72];
  const int r0 = blockIdx.x * 64;  // s-dim
  const int c0 = blockIdx.y * 64;  // d-dim
  const int tid = threadIdx.x;
#pragma unroll
  for (int it = 0; it < 2; ++it) {
    int t = tid + it * 256;
    int rr = t >> 3, cc = (t & 7) * 8;
    *(bf16x8*)&T[rr][cc] = *(const bf16x8*)(V + (size_t)(r0 + rr) * D_ + c0 + cc);
  }
  __syncthreads();
#pragma unroll
  for (int it = 0; it < 2; ++it) {
    int t = tid + it * 256;
    int cr = t >> 3, rc = (t & 7) * 8;
    bf16x8 v;
#pragma unroll
    for (int j = 0; j < 8; ++j) v[j] = T[rc + j][cr];
    *(bf16x8*)(Vt + (size_t)(c0 + cr) * 4096 + r0 + rc) = v;
  }
}

// ---------------------------------------------------------------------------
// GEMM 128x128: C[4096,1024] = A @ BT^T, BK=64, XOR-swizzled LDS. (qkv, z=3)
// ---------------------------------------------------------------------------
__global__ __launch_bounds__(256) void gemm_bt(
    const bf16_t* __restrict__ A0, const bf16_t* __restrict__ A1,
    const bf16_t* __restrict__ A2, const bf16_t* __restrict__ BT0,
    const bf16_t* __restrict__ BT1, const bf16_t* __restrict__ BT2,
    bf16_t* __restrict__ C0, bf16_t* __restrict__ C1, bf16_t* __restrict__ C2) {
  __shared__ __align__(16) bf16_t As[128 * 64];
  __shared__ __align__(16) bf16_t Bs[128 * 64];

  const int z = blockIdx.z;
  const bf16_t* A = (z == 0) ? A0 : (z == 1) ? A1 : A2;
  const bf16_t* BT = (z == 0) ? BT0 : (z == 1) ? BT1 : BT2;
  bf16_t* C = (z == 0) ? C0 : (z == 1) ? C1 : C2;

  const int tid = threadIdx.x;
  const int lane = tid & 63, wave = tid >> 6;
  const int l = lane & 15, quad = lane >> 4;
  const int wm = wave >> 1, wn = wave & 1;
  const int row0 = blockIdx.x * 128, col0 = blockIdx.y * 128;

  const int lr = lane >> 3;
  const int gc8 = (lane & 7) ^ lr;
  const int xl = l & 7;

  f32x4 acc[4][4];
#pragma unroll
  for (int i = 0; i < 4; ++i)
#pragma unroll
    for (int j = 0; j < 4; ++j) acc[i][j] = {0.f, 0.f, 0.f, 0.f};

  for (int k0 = 0; k0 < 1024; k0 += 64) {
    __syncthreads();
#pragma unroll
    for (int c = 0; c < 4; ++c) {
      int r = wave * 32 + c * 8;
      async16(A + (size_t)(row0 + r + lr) * 1024 + k0 + gc8 * 8, As + r * 64);
      async16(BT + (size_t)(col0 + r + lr) * 1024 + k0 + gc8 * 8, Bs + r * 64);
    }
    __syncthreads();

#pragma unroll
    for (int kh = 0; kh < 2; ++kh) {
      bf16x8 af[4], bf[4];
#pragma unroll
      for (int f = 0; f < 4; ++f)
        af[f] = *(const bf16x8*)&As[(wm * 64 + f * 16 + l) * 64 +
                                    (((kh * 4 + quad) ^ xl) * 8)];
#pragma unroll
      for (int f = 0; f < 4; ++f)
        bf[f] = *(const bf16x8*)&Bs[(wn * 64 + f * 16 + l) * 64 +
                                    (((kh * 4 + quad) ^ xl) * 8)];
#pragma unroll
      for (int fm = 0; fm < 4; ++fm)
#pragma unroll
        for (int fn = 0; fn < 4; ++fn)
          acc[fm][fn] = mfma16(af[fm], bf[fn], acc[fm][fn]);
    }
  }

#pragma unroll
  for (int fm = 0; fm < 4; ++fm)
#pragma unroll
    for (int fn = 0; fn < 4; ++fn)
#pragma unroll
      for (int reg = 0; reg < 4; ++reg) {
        int row = row0 + wm * 64 + fm * 16 + quad * 4 + reg;
        int col = col0 + wn * 64 + fn * 16 + l;
        C[(size_t)row * 1024 + col] = (bf16_t)acc[fm][fn][reg];
      }
}

// ---------------------------------------------------------------------------
// GEMM 64x128 (out-proj): out = A @ BT^T + bias, fp32 out. 512 blocks.
// ---------------------------------------------------------------------------
__global__ __launch_bounds__(256) void gemm_bt64(
    const bf16_t* __restrict__ A, const bf16_t* __restrict__ BT,
    float* __restrict__ C, const float* __restrict__ bias) {
  __shared__ __align__(16) bf16_t As[64 * 64];
  __shared__ __align__(16) bf16_t Bs[128 * 64];

  const int tid = threadIdx.x;
  const int lane = tid & 63, wave = tid >> 6;
  const int l = lane & 15, quad = lane >> 4;
  const int row0 = blockIdx.x * 64, col0 = blockIdx.y * 128;

  const int lr = lane >> 3;
  const int gc8 = (lane & 7) ^ lr;
  const int xl = l & 7;

  f32x4 acc[4][2];
#pragma unroll
  for (int i = 0; i < 4; ++i)
#pragma unroll
    for (int j = 0; j < 2; ++j) acc[i][j] = {0.f, 0.f, 0.f, 0.f};

  for (int k0 = 0; k0 < 1024; k0 += 64) {
    __syncthreads();
#pragma unroll
    for (int c = 0; c < 2; ++c) {
      int r = wave * 16 + c * 8;
      async16(A + (size_t)(row0 + r + lr) * 1024 + k0 + gc8 * 8, As + r * 64);
    }
#pragma unroll
    for (int c = 0; c < 4; ++c) {
      int r = wave * 32 + c * 8;
      async16(BT + (size_t)(col0 + r + lr) * 1024 + k0 + gc8 * 8, Bs + r * 64);
    }
    __syncthreads();

#pragma unroll
    for (int kh = 0; kh < 2; ++kh) {
      bf16x8 af[4], bf[2];
#pragma unroll
      for (int f = 0; f < 4; ++f)
        af[f] = *(const bf16x8*)&As[(f * 16 + l) * 64 +
                                    (((kh * 4 + quad) ^ xl) * 8)];
#pragma unroll
      for (int f = 0; f < 2; ++f)
        bf[f] = *(const bf16x8*)&Bs[(wave * 32 + f * 16 + l) * 64 +
                                    (((kh * 4 + quad) ^ xl) * 8)];
#pragma unroll
      for (int fm = 0; fm < 4; ++fm)
#pragma unroll
        for (int fn = 0; fn < 2; ++fn)
          acc[fm][fn] = mfma16(af[fm], bf[fn], acc[fm][fn]);
    }
  }

#pragma unroll
  for (int fm = 0; fm < 4; ++fm)
#pragma unroll
    for (int fn = 0; fn < 2; ++fn)
#pragma unroll
      for (int reg = 0; reg < 4; ++reg) {
        int row = row0 + fm * 16 + quad * 4 + reg;
        int col = col0 + wave * 32 + fn * 16 + l;
        C[(size_t)row * 1024 + col] = acc[fm][fn][reg] + bias[col];
      }
}

// ---------------------------------------------------------------------------
// Flash attention, transposed-score, R8 2-wave form + t-split over 2 blocks.
// blockIdx.x: qt = x>>1, split = x&1 (t range split*1024 .. +1023).
// Writes bf16 o-partials (po0/po1) and fp32 lsum partials (no divide here).
// ---------------------------------------------------------------------------
__global__ __launch_bounds__(128) void attn_kernel(
    const bf16_t* __restrict__ Qx, const bf16_t* __restrict__ Kx,
    const bf16_t* __restrict__ Vt, const u32* __restrict__ mbits,
    bf16_t* __restrict__ po0, bf16_t* __restrict__ po1,
    float* __restrict__ ls) {
  __shared__ __align__(16) bf16_t Ks[64 * 64];    // [t][dk] swizzled
  __shared__ __align__(16) bf16_t Vts[64 * 64];   // [d][t]  swizzled
  __shared__ __align__(16) bf16_t Ps[2][32][72];  // per-wave P [q][t]

  const int tid = threadIdx.x;
  const int lane = tid & 63, wave = tid >> 6;  // 2 waves
  const int l = lane & 15, quad = lane >> 4;
  const int qt = blockIdx.x >> 1, split = blockIdx.x & 1;
  const int h = blockIdx.y, b = blockIdx.z;
  const int ch = h * 64;
  const size_t rb = (size_t)b * S_;
  const int q0 = qt * 64 + wave * 32;
  const int tbeg = split * (S_ / 2), tend = tbeg + S_ / 2;

  const int lr = lane >> 3;
  const int gc8 = (lane & 7) ^ lr;
  const int xl = l & 7;

  // Q B-frags: bq[mf][kc], B[n=q=l][k=dk]
  bf16x8 bq[2][2];
#pragma unroll
  for (int mf = 0; mf < 2; ++mf) {
    const bf16_t* qp = Qx + (rb + q0 + mf * 16 + l) * D_ + ch;
    bq[mf][0] = *(const bf16x8*)(qp + quad * 8);
    bq[mf][1] = *(const bf16x8*)(qp + 32 + quad * 8);
  }

  const f32x4 zero = {0.f, 0.f, 0.f, 0.f};
  f32x4 o[2][4];
  float lsum[2] = {0.f, 0.f};
#pragma unroll
  for (int mf = 0; mf < 2; ++mf)
#pragma unroll
    for (int nt = 0; nt < 4; ++nt) o[mf][nt] = zero;

  const u32* mrow[2];
#pragma unroll
  for (int mf = 0; mf < 2; ++mf)
    mrow[mf] = mbits + (size_t)(b * S_ + q0 + mf * 16 + l) * (S_ / 32);

  for (int t0 = tbeg; t0 < tend; t0 += 64) {
    __syncthreads();
#pragma unroll
    for (int it = 0; it < 4; ++it) {
      int r0 = it * 16 + wave * 8;
      async16(Kx + (rb + t0 + r0 + lr) * D_ + ch + gc8 * 8, Ks + r0 * 64);
      async16(Vt + (size_t)(ch + r0 + lr) * 4096 + rb + t0 + gc8 * 8,
              Vts + r0 * 64);
    }
    __syncthreads();

    // S' = K.Q^T: D[m=t=quad*4+reg][n=q=l]
#pragma unroll
    for (int mf = 0; mf < 2; ++mf) {
      u32 mw0 = mrow[mf][(t0 >> 5)];
      u32 mw1 = mrow[mf][(t0 >> 5) + 1];
#pragma unroll
      for (int ts = 0; ts < 4; ++ts) {
        int rK = (ts * 16 + l) * 64;
        bf16x8 ak0 = *(const bf16x8*)&Ks[rK + ((quad ^ xl) * 8)];
        bf16x8 ak1 = *(const bf16x8*)&Ks[rK + (((4 + quad) ^ xl) * 8)];
        f32x4 s = mfma16(ak0, bq[mf][0], zero);
        s = mfma16(ak1, bq[mf][1], s);

        u32 mw = (ts < 2) ? mw0 : mw1;
        u32 nib = (mw >> ((ts & 1) * 16 + quad * 4)) & 0xFu;
        bf16x4 pv;
#pragma unroll
        for (int reg = 0; reg < 4; ++reg) {
          float e = __expf(fminf(s[reg], 30.0f));
          float pp = ((nib >> reg) & 1u) ? e : 0.0f;
          lsum[mf] += pp;
          pv[reg] = (bf16_t)pp;
        }
        *(bf16x4*)&Ps[wave][mf * 16 + l][ts * 16 + quad * 4] = pv;
      }
    }

    // PV: O[q][d] += P.V^T
    bf16x8 ap[2][2];
#pragma unroll
    for (int mf = 0; mf < 2; ++mf) {
      ap[mf][0] = *(const bf16x8*)&Ps[wave][mf * 16 + l][quad * 8];
      ap[mf][1] = *(const bf16x8*)&Ps[wave][mf * 16 + l][32 + quad * 8];
    }
#pragma unroll
    for (int nt = 0; nt < 4; ++nt) {
      int rV = (nt * 16 + l) * 64;
      bf16x8 bv0 = *(const bf16x8*)&Vts[rV + ((quad ^ xl) * 8)];
      bf16x8 bv1 = *(const bf16x8*)&Vts[rV + (((4 + quad) ^ xl) * 8)];
#pragma unroll
      for (int mf = 0; mf < 2; ++mf) {
        o[mf][nt] = mfma16(ap[mf][0], bv0, o[mf][nt]);
        o[mf][nt] = mfma16(ap[mf][1], bv1, o[mf][nt]);
      }
    }
  }

  // epilogue: publish partials — no divide (merge kernel handles it)
  bf16_t* po = split ? po1 : po0;
#pragma unroll
  for (int mf = 0; mf < 2; ++mf) {
    float rsum = lsum[mf];
    rsum += __shfl_xor(rsum, 16);
    rsum += __shfl_xor(rsum, 32);
    if (quad == 0)
      ls[(size_t)split * (B_ * S_ * H_) + (rb + q0 + mf * 16 + l) * H_ + h] = rsum;
#pragma unroll
    for (int reg = 0; reg < 4; ++reg) {
      int srow = q0 + mf * 16 + quad * 4 + reg;
      bf16_t* op = po + (rb + srow) * D_ + ch;
#pragma unroll
      for (int nt = 0; nt < 4; ++nt)
        op[nt * 16 + l] = (bf16_t)o[mf][nt][reg];
    }
  }
}

// ---------------------------------------------------------------------------
// Merge: ab = (po0 + po1) / (l0 + l1). 8 cols/thread, 2048 blocks.
// ---------------------------------------------------------------------------
__global__ __launch_bounds__(256) void attn_merge(
    const bf16_t* __restrict__ po0, const bf16_t* __restrict__ po1,
    const float* __restrict__ ls, bf16_t* __restrict__ ab) {
  int idx = blockIdx.x * 256 + threadIdx.x;
  int r = idx >> 7;             // row 0..4095
  int c8 = (idx & 127) * 8;     // col group
  int hh = c8 >> 6;
  float l0 = ls[(size_t)r * H_ + hh];
  float l1 = ls[(size_t)(B_ * S_ * H_) + (size_t)r * H_ + hh];
  float sum = l0 + l1;
  float inv = (sum > 0.f) ? (1.f / sum) : 0.f;
  bf16x8 a = *(const bf16x8*)(po0 + (size_t)r * D_ + c8);
  bf16x8 b = *(const bf16x8*)(po1 + (size_t)r * D_ + c8);
  bf16x8 o;
#pragma unroll
  for (int j = 0; j < 8; ++j) o[j] = (bf16_t)(((float)a[j] + (float)b[j]) * inv);
  *(bf16x8*)(ab + (size_t)r * D_ + c8) = o;
}

// ---------------------------------------------------------------------------
extern "C" void kernel_launch(void* const* d_in, const int* in_sizes, int n_in,
                              void* d_out, int out_size, void* d_ws, size_t ws_size,
                              hipStream_t stream) {
  const float* q_in = (const float*)d_in[0];
  const float* k_in = (const float*)d_in[1];
  const float* v_in = (const float*)d_in[2];
  const int* mask = (const int*)d_in[3];
  const float* Wq = (const float*)d_in[4];
  const float* Wk = (const float*)d_in[5];
  const float* Wv = (const float*)d_in[6];
  const float* Wu = (const float*)d_in[7];
  const float* bu = (const float*)d_in[8];
  float* outp = (float*)d_out;

  bf16_t* qx = (bf16_t*)d_ws;
  bf16_t* kx = qx + NX_;
  bf16_t* vx = kx + NX_;
  bf16_t* qb = vx + NX_;
  bf16_t* kb = qb + NX_;
  bf16_t* vb = kb + NX_;
  bf16_t* BTq = vb + NX_;
  bf16_t* BTk = BTq + D_ * D_;
  bf16_t* BTv = BTk + D_ * D_;
  bf16_t* BTu = BTv + D_ * D_;
  u32* mb = (u32*)(BTu + D_ * D_);
  float* ls = (float*)(mb + B_ * S_ * S_ / 32);  // 2 x [B*S][H] fp32
  bf16_t* ab = qx;   // qx dead after qkv gemm
  bf16_t* vtb = kx;  // kx dead after qkv gemm
  bf16_t* po0 = vx;  // vx dead after qkv gemm
  bf16_t* po1 = vb;  // vb dead after vt_build

  const float qkscale = 0.35355339059327373f;  // 1 / 64^0.25

  dim3 blk(256);
  prep<<<dim3(2048, 5), blk, 0, stream>>>(q_in, k_in, v_in, mask, Wq, Wk, Wv, Wu,
                                          qx, kx, vx, BTq, BTk, BTv, BTu, mb,
                                          qkscale);
  gemm_bt<<<dim3(32, 8, 3), blk, 0, stream>>>(qx, kx, vx, BTq, BTk, BTv,
                                              qb, kb, vb);
  vt_build<<<dim3(64, 16), blk, 0, stream>>>(vb, vtb);
  attn_kernel<<<dim3(S_ / 32, H_, B_), dim3(128), 0, stream>>>(qb, kb, vtb, mb,
                                                               po0, po1, ls);
  attn_merge<<<dim3(2048), blk, 0, stream>>>(po0, po1, ls, ab);
  gemm_bt64<<<dim3(64, 8), blk, 0, stream>>>(ab, BTu, outp, bu);
}